// Round 11
// baseline (15518.159 us; speedup 1.0000x reference)
//
#include <hip/hip_runtime.h>
#include <hip/hip_bf16.h>
#include <stdint.h>

typedef _Float16 f16_t;
typedef f16_t f16x8_t __attribute__((ext_vector_type(8)));
typedef f16_t f16x4_t __attribute__((ext_vector_type(4)));
typedef float f32x4_t __attribute__((ext_vector_type(4)));

#define NROWS 8192
#define DDIM  4096
#define BK 32
#define KTILES (DDIM / BK)  // 128
#define LSTR 40             // slow-path LDS stride

// ---------------- async 16B global->LDS ----------------
__device__ __forceinline__ void gload16(const void* g, void* s) {
  __builtin_amdgcn_global_load_lds(
      (const __attribute__((address_space(1))) void*)g,
      (__attribute__((address_space(3))) void*)s, 16, 0, 0);
}

// ---------------- presplit: fp32 -> (hi,lo) f16 ----------------
__global__ __launch_bounds__(256) void k_split(const float* __restrict__ in,
                                               f16_t* __restrict__ hi,
                                               f16_t* __restrict__ lo) {
  const long i = ((long)blockIdx.x * 256 + threadIdx.x) * 4;
  const float4 v = *reinterpret_cast<const float4*>(in + i);
  float vv[4] = {v.x, v.y, v.z, v.w};
  f16x4_t h, l;
#pragma unroll
  for (int c = 0; c < 4; ++c) {
    f16_t hh = (f16_t)vv[c];
    h[c] = hh;
    l[c] = (f16_t)(vv[c] - (float)hh);
  }
  *reinterpret_cast<f16x4_t*>(hi + i) = h;
  *reinterpret_cast<f16x4_t*>(lo + i) = l;
}

// ======================= GEMM1 core: split-f16 3-pass, 2 barriers/K-tile ============
// 16x16x32 fragments (proven zero-conflict). T2 swizzle: phys 16B-granule
// p = g ^ ((row>>1)&3); inverse on per-lane global source granule, XOR on ds_read col.
// 80 KiB LDS -> 2 blocks/CU: Al double-buffered; Ah,Bh,Bl single-buffered (their reads
// retire in phase 0; next-tile issues happen after the mid barrier).
typedef struct {
  f16_t Al[2][256][BK];  // 32 KiB
  f16_t Ah[256][BK];     // 16 KiB
  f16_t Bh[256][BK];     // 16 KiB
  f16_t Bl[256][BK];     // 16 KiB
} lds_g1_t;              // 80 KiB

__device__ __forceinline__ void gemm_core256_g1(
    const f16_t* __restrict__ pAh, const f16_t* __restrict__ pAl, long lda,
    const f16_t* __restrict__ pBh, const f16_t* __restrict__ pBl, long ldb,
    lds_g1_t* sm, f32x4_t (&acc)[8][4]) {
  const int t = threadIdx.x, lane = t & 63, w = t >> 6;
  const int fr = lane & 15, kg = lane >> 4;
  const int wr = (w >> 2) * 128, wc = (w & 3) * 64;
  const int w32 = w * 32;
  const int sr0 = w32 + (lane >> 2);
  const int sg = (((lane & 3) ^ ((lane >> 3) & 3)) * 8);
  const int kge = (kg ^ ((fr >> 1) & 3)) * 8;

#pragma unroll
  for (int m = 0; m < 8; ++m)
#pragma unroll
    for (int n = 0; n < 4; ++n) acc[m][n] = f32x4_t{0.f, 0.f, 0.f, 0.f};

  const f16_t* gAh = pAh + (long)sr0 * lda + sg;
  const f16_t* gAl = pAl + (long)sr0 * lda + sg;
  const f16_t* gBh = pBh + (long)sr0 * ldb + sg;
  const f16_t* gBl = pBl + (long)sr0 * ldb + sg;
  const long a16 = 16 * lda, b16 = 16 * ldb;

  auto issue2 = [&](f16_t (*plane)[BK], const f16_t* g, long ld16, int k0) {
    gload16(g + k0, &plane[w32][0]);
    gload16(g + ld16 + k0, &plane[w32 + 16][0]);
  };

  f16x8_t ah[8], al[8], bh[4], bl[4];
  auto read8 = [&](f16x8_t(&R)[8], const f16_t (*plane)[BK]) {
#pragma unroll
    for (int m = 0; m < 8; ++m)
      R[m] = *reinterpret_cast<const f16x8_t*>(&plane[wr + m * 16 + fr][kge]);
  };
  auto read4 = [&](f16x8_t(&R)[4], const f16_t (*plane)[BK]) {
#pragma unroll
    for (int n = 0; n < 4; ++n)
      R[n] = *reinterpret_cast<const f16x8_t*>(&plane[wc + n * 16 + fr][kge]);
  };
  auto mfma32 = [&](f16x8_t(&A)[8], f16x8_t(&B)[4]) {
    __builtin_amdgcn_s_setprio(1);
#pragma unroll
    for (int m = 0; m < 8; ++m)
#pragma unroll
      for (int n = 0; n < 4; ++n)
        acc[m][n] = __builtin_amdgcn_mfma_f32_16x16x32_f16(A[m], B[n], acc[m][n], 0, 0, 0);
    __builtin_amdgcn_s_setprio(0);
  };

  // prologue: FIFO order Ah,Bh,Bl (waited), then Al (left outstanding)
  issue2(sm->Ah, gAh, a16, 0);
  issue2(sm->Bh, gBh, b16, 0);
  issue2(sm->Bl, gBl, b16, 0);
  issue2(sm->Al[0], gAl, a16, 0);
  asm volatile("s_waitcnt vmcnt(2)" ::: "memory");  // Ah,Bh,Bl(0) landed
  __builtin_amdgcn_s_barrier();

  for (int kt = 0; kt < KTILES - 1; ++kt) {
    const int c = kt & 1;
    const int k0 = (kt + 1) * BK;
    // phase 0: reads of all single planes retire here
    read8(ah, sm->Ah);
    read4(bh, sm->Bh);
    read4(bl, sm->Bl);
    mfma32(ah, bh);
    mfma32(ah, bl);
    asm volatile("s_waitcnt vmcnt(0)" ::: "memory");  // Al(kt) landed (issued 1.5kt ago)
    __builtin_amdgcn_s_barrier();                     // mid
    // phase 1: safe to overwrite single planes; prefetch everything for kt+1
    issue2(sm->Ah, gAh, a16, k0);
    issue2(sm->Bh, gBh, b16, k0);
    issue2(sm->Bl, gBl, b16, k0);
    issue2(sm->Al[c ^ 1], gAl, a16, k0);
    read8(al, sm->Al[c]);
    mfma32(al, bh);
    asm volatile("s_waitcnt vmcnt(2)" ::: "memory");  // Ah,Bh,Bl(kt+1) landed
    __builtin_amdgcn_s_barrier();                     // end
  }
  // peeled last tile
  {
    const int c = (KTILES - 1) & 1;
    read8(ah, sm->Ah);
    read4(bh, sm->Bh);
    read4(bl, sm->Bl);
    mfma32(ah, bh);
    mfma32(ah, bl);
    asm volatile("s_waitcnt vmcnt(0)" ::: "memory");  // Al(last) landed
    __builtin_amdgcn_s_barrier();
    read8(al, sm->Al[c]);
    mfma32(al, bh);
  }
}

// ---------------- GEMM1 fast: xp(hi,lo f16) = split(relu(x @ W^T + b)) ----------------
__global__ __launch_bounds__(512, 4) void k_gemm1_256(
    const f16_t* __restrict__ xh, const f16_t* __restrict__ xl,
    const f16_t* __restrict__ Wh, const f16_t* __restrict__ Wl,
    const float* __restrict__ bias,
    f16_t* __restrict__ xph, f16_t* __restrict__ xpl) {
  extern __shared__ char smraw[];
  lds_g1_t* sm = (lds_g1_t*)smraw;

  int bid = (int)blockIdx.x;
  bid = (bid & 7) * 64 + (bid >> 3);  // 512 blocks, XCD-chunked (bijective)
  const int bx = bid & 15, by = bid >> 4;
  const long brow = (long)by * 256, bcol = (long)bx * 256;

  f32x4_t acc[8][4];
  gemm_core256_g1(xh + brow * DDIM, xl + brow * DDIM, DDIM,
                  Wh + bcol * DDIM, Wl + bcol * DDIM, DDIM, sm, acc);

  const int t = threadIdx.x, lane = t & 63, w = t >> 6;
  const int wr = (w >> 2) * 128, wc = (w & 3) * 64;
  const int cr = (lane >> 4) * 4, cc = lane & 15;
#pragma unroll
  for (int n = 0; n < 4; ++n) {
    const long col = bcol + wc + n * 16 + cc;
    const float bb = bias[col];
#pragma unroll
    for (int m = 0; m < 8; ++m) {
      const long row0 = brow + wr + m * 16 + cr;
#pragma unroll
      for (int r = 0; r < 4; ++r) {
        const float v = fmaxf(acc[m][n][r] + bb, 0.f);
        const f16_t h = (f16_t)v;
        xph[(row0 + r) * (long)DDIM + col] = h;
        xpl[(row0 + r) * (long)DDIM + col] = (f16_t)(v - (float)h);
      }
    }
  }
}

// ======================= GEMM2 core: Ah*(Bh+Bl), 2 barriers/K-tile ==================
// 80 KiB LDS -> 2 blocks/CU: Bh,Bl double-buffered; Ah single (reads retire phase 0,
// reissue after mid barrier). Parametrized K range for the K-split.
typedef struct {
  f16_t Bh[2][256][BK];  // 32 KiB
  f16_t Bl[2][256][BK];  // 32 KiB
  f16_t Ah[256][BK];     // 16 KiB
} lds_g2_t;              // 80 KiB

__device__ __forceinline__ void gemm_core256_g2(
    const f16_t* __restrict__ pAh, long lda,
    const f16_t* __restrict__ pBh, const f16_t* __restrict__ pBl, long ldb,
    lds_g2_t* sm, f32x4_t (&acc)[8][4], int kt0, int ktn) {
  const int t = threadIdx.x, lane = t & 63, w = t >> 6;
  const int fr = lane & 15, kg = lane >> 4;
  const int wr = (w >> 2) * 128, wc = (w & 3) * 64;
  const int w32 = w * 32;
  const int sr0 = w32 + (lane >> 2);
  const int sg = (((lane & 3) ^ ((lane >> 3) & 3)) * 8);
  const int kge = (kg ^ ((fr >> 1) & 3)) * 8;

#pragma unroll
  for (int m = 0; m < 8; ++m)
#pragma unroll
    for (int n = 0; n < 4; ++n) acc[m][n] = f32x4_t{0.f, 0.f, 0.f, 0.f};

  const f16_t* gAh = pAh + (long)sr0 * lda + sg;
  const f16_t* gBh = pBh + (long)sr0 * ldb + sg;
  const f16_t* gBl = pBl + (long)sr0 * ldb + sg;
  const long a16 = 16 * lda, b16 = 16 * ldb;

  auto issue2 = [&](f16_t (*plane)[BK], const f16_t* g, long ld16, int k0) {
    gload16(g + k0, &plane[w32][0]);
    gload16(g + ld16 + k0, &plane[w32 + 16][0]);
  };

  f16x8_t ah[8], bh[4], bl[4];
  auto read8 = [&](f16x8_t(&R)[8], const f16_t (*plane)[BK]) {
#pragma unroll
    for (int m = 0; m < 8; ++m)
      R[m] = *reinterpret_cast<const f16x8_t*>(&plane[wr + m * 16 + fr][kge]);
  };
  auto read4 = [&](f16x8_t(&R)[4], const f16_t (*plane)[BK]) {
#pragma unroll
    for (int n = 0; n < 4; ++n)
      R[n] = *reinterpret_cast<const f16x8_t*>(&plane[wc + n * 16 + fr][kge]);
  };
  auto mfma32 = [&](f16x8_t(&A)[8], f16x8_t(&B)[4]) {
    __builtin_amdgcn_s_setprio(1);
#pragma unroll
    for (int m = 0; m < 8; ++m)
#pragma unroll
      for (int n = 0; n < 4; ++n)
        acc[m][n] = __builtin_amdgcn_mfma_f32_16x16x32_f16(A[m], B[n], acc[m][n], 0, 0, 0);
    __builtin_amdgcn_s_setprio(0);
  };

  // prologue: FIFO Bh,Ah (waited), Bl (left outstanding)
  const int kb = kt0 * BK;
  issue2(sm->Bh[0], gBh, b16, kb);
  issue2(sm->Ah, gAh, a16, kb);
  issue2(sm->Bl[0], gBl, b16, kb);
  asm volatile("s_waitcnt vmcnt(2)" ::: "memory");  // Bh,Ah(0) landed
  __builtin_amdgcn_s_barrier();

  for (int it = 0; it < ktn - 1; ++it) {
    const int c = it & 1;
    const int k0 = (kt0 + it + 1) * BK;
    // phase 0
    issue2(sm->Bh[c ^ 1], gBh, b16, k0);
    read8(ah, sm->Ah);
    read4(bh, sm->Bh[c]);
    mfma32(ah, bh);
    asm volatile("s_waitcnt vmcnt(2)" ::: "memory");  // Bl(it) landed
    __builtin_amdgcn_s_barrier();                     // mid
    // phase 1: Ah reads retired -> reissue single plane
    issue2(sm->Ah, gAh, a16, k0);
    issue2(sm->Bl[c ^ 1], gBl, b16, k0);
    read4(bl, sm->Bl[c]);
    mfma32(ah, bl);
    asm volatile("s_waitcnt vmcnt(2)" ::: "memory");  // Bh,Ah(it+1) landed
    __builtin_amdgcn_s_barrier();                     // end
  }
  // peeled last tile
  {
    const int c = (ktn - 1) & 1;
    read8(ah, sm->Ah);
    read4(bh, sm->Bh[c]);
    mfma32(ah, bh);
    asm volatile("s_waitcnt vmcnt(0)" ::: "memory");  // Bl(last) landed
    __builtin_amdgcn_s_barrier();
    read4(bl, sm->Bl[c]);
    mfma32(ah, bl);
  }
}

// -------- GEMM2: SPLITK: 1056 jobs = (528 lower-tri tiles) x (2 K-halves).
// khalf=0 writes scores+recency to out; khalf=1 writes raw partial to part[tidx].
// Softmax merges. Non-SPLITK fallback: 528 full-K tiles, no partial.
template <bool SPLITK>
__global__ __launch_bounds__(512, 4) void k_gemm2(
    const f16_t* __restrict__ xph, const f16_t* __restrict__ xpl,
    const float* __restrict__ rwp, float* __restrict__ out,
    float* __restrict__ part) {
  extern __shared__ char smraw[];
  lds_g2_t* sm = (lds_g2_t*)smraw;

  int id = (int)blockIdx.x;
  int tidx, khalf;
  if (SPLITK) {
    id = (id & 7) * 132 + (id >> 3);  // 1056 = 8*132, bijective XCD chunking
    khalf = (id >= 528) ? 1 : 0;
    tidx = id - khalf * 528;
  } else {
    id = (id & 7) * 66 + (id >> 3);   // 528 = 8*66
    khalf = 0;
    tidx = id;
  }
  int by = (int)((sqrtf(8.f * (float)tidx + 1.f) - 1.f) * 0.5f);
  while ((by + 1) * (by + 2) / 2 <= tidx) ++by;
  while (by * (by + 1) / 2 > tidx) --by;
  const int bx = tidx - by * (by + 1) / 2;  // 0 <= bx <= by

  const long brow = (long)by * 256, bcol = (long)bx * 256;
  f32x4_t acc[8][4];
  gemm_core256_g2(xph + brow * DDIM, DDIM,
                  xph + bcol * DDIM, xpl + bcol * DDIM, DDIM, sm, acc,
                  SPLITK ? khalf * (KTILES / 2) : 0, SPLITK ? (KTILES / 2) : KTILES);

  const int t = threadIdx.x, lane = t & 63, w = t >> 6;
  const int wr = (w >> 2) * 128, wc = (w & 3) * 64;
  const int cr = (lane >> 4) * 4, cc = lane & 15;

  if (!SPLITK || khalf == 0) {
    const float rw = rwp[0];
#pragma unroll
    for (int n = 0; n < 4; ++n) {
      const long gj = bcol + wc + n * 16 + cc;
#pragma unroll
      for (int m = 0; m < 8; ++m) {
        const long gi0 = brow + wr + m * 16 + cr;
#pragma unroll
        for (int r = 0; r < 4; ++r) {
          const long gi = gi0 + r;
          out[gi * (long)NROWS + gj] = acc[m][n][r] + rw * (float)(gi - gj);
        }
      }
    }
  } else {
    float* pt = part + (size_t)tidx * 65536;
#pragma unroll
    for (int n = 0; n < 4; ++n) {
      const int lj = wc + n * 16 + cc;
#pragma unroll
      for (int m = 0; m < 8; ++m) {
        const int li0 = wr + m * 16 + cr;
#pragma unroll
        for (int r = 0; r < 4; ++r) {
          pt[(li0 + r) * 256 + lj] = acc[m][n][r];
        }
      }
    }
  }
}

// ---------------- slow-path GEMM1 (fp32 in-LDS split; fallback) ----------------
__device__ __forceinline__ void stage_split(const float* __restrict__ src, long ld,
                                            f16_t (&hi)[128][LSTR],
                                            f16_t (&lo)[128][LSTR],
                                            int t) {
#pragma unroll
  for (int i = 0; i < 4; ++i) {
    const int f = i * 256 + t;
    const int row = f >> 3;
    const int kq = (f & 7) << 2;
    const float4 v = *reinterpret_cast<const float4*>(src + (long)row * ld + kq);
    float vv[4] = {v.x, v.y, v.z, v.w};
    f16x4_t h, l;
#pragma unroll
    for (int c = 0; c < 4; ++c) {
      f16_t hh = (f16_t)vv[c];
      h[c] = hh;
      l[c] = (f16_t)(vv[c] - (float)hh);
    }
    *reinterpret_cast<f16x4_t*>(&hi[row][kq]) = h;
    *reinterpret_cast<f16x4_t*>(&lo[row][kq]) = l;
  }
}

__global__ __launch_bounds__(256) void k_gemm1_slow(
    const float* __restrict__ x, const float* __restrict__ W,
    const float* __restrict__ bias,
    f16_t* __restrict__ xph, f16_t* __restrict__ xpl) {
  __shared__ alignas(16) f16_t Ahi[128][LSTR];
  __shared__ alignas(16) f16_t Alo[128][LSTR];
  __shared__ alignas(16) f16_t Bhi[128][LSTR];
  __shared__ alignas(16) f16_t Blo[128][LSTR];

  const long brow = (long)blockIdx.y * 128;
  const long bcol = (long)blockIdx.x * 128;
  const int t = threadIdx.x, lane = t & 63;
  const int wr = ((t >> 6) >> 1) * 64, wc = ((t >> 6) & 1) * 64;
  const int fr = lane & 15, kg = lane >> 4;

  f32x4_t acc[4][4];
#pragma unroll
  for (int m = 0; m < 4; ++m)
#pragma unroll
    for (int n = 0; n < 4; ++n) acc[m][n] = f32x4_t{0.f, 0.f, 0.f, 0.f};

  const float* Abase = x + brow * DDIM;
  const float* Bbase = W + bcol * DDIM;
  for (int k0 = 0; k0 < DDIM; k0 += BK) {
    __syncthreads();
    stage_split(Abase + k0, DDIM, Ahi, Alo, t);
    stage_split(Bbase + k0, DDIM, Bhi, Blo, t);
    __syncthreads();

    f16x8_t ah[4], al[4], bh[4], bl[4];
#pragma unroll
    for (int m = 0; m < 4; ++m) {
      ah[m] = *reinterpret_cast<const f16x8_t*>(&Ahi[wr + m * 16 + fr][kg * 8]);
      al[m] = *reinterpret_cast<const f16x8_t*>(&Alo[wr + m * 16 + fr][kg * 8]);
      bh[m] = *reinterpret_cast<const f16x8_t*>(&Bhi[wc + m * 16 + fr][kg * 8]);
      bl[m] = *reinterpret_cast<const f16x8_t*>(&Blo[wc + m * 16 + fr][kg * 8]);
    }
#pragma unroll
    for (int m = 0; m < 4; ++m)
#pragma unroll
      for (int n = 0; n < 4; ++n) {
        acc[m][n] = __builtin_amdgcn_mfma_f32_16x16x32_f16(ah[m], bh[n], acc[m][n], 0, 0, 0);
        acc[m][n] = __builtin_amdgcn_mfma_f32_16x16x32_f16(ah[m], bl[n], acc[m][n], 0, 0, 0);
        acc[m][n] = __builtin_amdgcn_mfma_f32_16x16x32_f16(al[m], bh[n], acc[m][n], 0, 0, 0);
      }
  }

  const int cr = (lane >> 4) * 4, cc = lane & 15;
#pragma unroll
  for (int n = 0; n < 4; ++n) {
    const long col = bcol + wc + n * 16 + cc;
    const float bb = bias[col];
#pragma unroll
    for (int m = 0; m < 4; ++m) {
      const long row0 = brow + wr + m * 16 + cr;
#pragma unroll
      for (int r = 0; r < 4; ++r) {
        const float v = fmaxf(acc[m][n][r] + bb, 0.f);
        const f16_t h = (f16_t)v;
        xph[(row0 + r) * (long)DDIM + col] = h;
        xpl[(row0 + r) * (long)DDIM + col] = (f16_t)(v - (float)h);
      }
    }
  }
}

// ------------- row softmax (online max+sum, single read pass), zeros for j>=i.
// part != nullptr: logits = out[i][j] + part[tile(i,j)][i%256][j%256] (K-split merge).
__global__ __launch_bounds__(256) void k_row_softmax(float* __restrict__ out,
                                                     const float* __restrict__ part,
                                                     int n) {
  const int i = blockIdx.x;
  float* row = out + (size_t)i * n;
  const int L = i;
  const int t = threadIdx.x;
  __shared__ float redm[4], reds[4];

  const int rt = i >> 8;
  const float* prow =
      part ? (part + ((size_t)(rt * (rt + 1) / 2) << 16) + ((size_t)(i & 255) << 8)) : nullptr;

  auto val = [&](int j) -> float {
    float v = row[j];
    if (part) v += prow[((size_t)(j >> 8) << 16) + (j & 255)];
    return v;
  };

  float m = -3.0e38f, s = 0.f;  // finite sentinel: avoids (-inf)-(-inf)=NaN in combines
  for (int j = t; j < L; j += 256) {
    const float v = val(j);
    const float M = fmaxf(m, v);
    s = s * __expf(m - M) + __expf(v - M);
    m = M;
  }
#pragma unroll
  for (int o = 32; o > 0; o >>= 1) {
    const float om = __shfl_down(m, o, 64);
    const float os = __shfl_down(s, o, 64);
    const float M = fmaxf(m, om);
    s = s * __expf(m - M) + os * __expf(om - M);
    m = M;
  }
  if ((t & 63) == 0) { redm[t >> 6] = m; reds[t >> 6] = s; }
  __syncthreads();
  const float M4 = fmaxf(fmaxf(redm[0], redm[1]), fmaxf(redm[2], redm[3]));
  const float S4 = reds[0] * __expf(redm[0] - M4) + reds[1] * __expf(redm[1] - M4) +
                   reds[2] * __expf(redm[2] - M4) + reds[3] * __expf(redm[3] - M4);
  const float inv = (L > 0) ? 1.f / S4 : 0.f;

  for (int j = t; j < n; j += 256) {
    row[j] = (j < L) ? __expf(val(j) - M4) * inv : 0.f;
  }
}

extern "C" void kernel_launch(void* const* d_in, const int* in_sizes, int n_in,
                              void* d_out, int out_size, void* d_ws, size_t ws_size,
                              hipStream_t stream) {
  (void)in_sizes; (void)n_in; (void)out_size;
  const float* x = (const float*)d_in[0];
  const float* W = (const float*)d_in[1];
  const float* b = (const float*)d_in[2];
  const float* rw = (const float*)d_in[3];
  float* out = (float*)d_out;

  const size_t NX = (size_t)NROWS * DDIM;
  const size_t NW = (size_t)DDIM * DDIM;
  char* ws = (char*)d_ws;
  f16_t* xph = (f16_t*)ws;
  f16_t* xpl = (f16_t*)(ws + NX * 2);

  const int LDSB1 = (int)sizeof(lds_g1_t);  // 81920 B
  const int LDSB2 = (int)sizeof(lds_g2_t);  // 81920 B
  (void)hipFuncSetAttribute(reinterpret_cast<const void*>(k_gemm1_256),
                            hipFuncAttributeMaxDynamicSharedMemorySize, LDSB1);
  (void)hipFuncSetAttribute(reinterpret_cast<const void*>(&k_gemm2<true>),
                            hipFuncAttributeMaxDynamicSharedMemorySize, LDSB2);
  (void)hipFuncSetAttribute(reinterpret_cast<const void*>(&k_gemm2<false>),
                            hipFuncAttributeMaxDynamicSharedMemorySize, LDSB2);

  const size_t need_full = NX * 4 /*xph,xpl*/ + NX * 4 /*xh,xl*/ + NW * 4 /*Wh,Wl*/;
  if (ws_size >= need_full) {
    f16_t* xh = (f16_t*)(ws + NX * 4);
    f16_t* xl = (f16_t*)(ws + NX * 6);
    f16_t* Wh = (f16_t*)(ws + NX * 8);
    f16_t* Wl = (f16_t*)(ws + NX * 8 + NW * 2);
    // K-split partial buffer reuses the xh/xl region (dead after k_gemm1_256):
    // 528 tiles * 65536 * 4B = 138.4 MB < NX*4 + NW*4 = 201 MB available.
    float* part = (float*)(ws + NX * 4);
    k_split<<<(int)(NX / 1024), 256, 0, stream>>>(x, xh, xl);
    k_split<<<(int)(NW / 1024), 256, 0, stream>>>(W, Wh, Wl);
    k_gemm1_256<<<512, 512, LDSB1, stream>>>(xh, xl, Wh, Wl, b, xph, xpl);
    k_gemm2<true><<<1056, 512, LDSB2, stream>>>(xph, xpl, rw, out, part);
    k_row_softmax<<<NROWS, 256, 0, stream>>>(out, part, NROWS);
  } else {
    k_gemm1_slow<<<dim3(DDIM / 128, NROWS / 128), 256, 0, stream>>>(x, W, b, xph, xpl);
    k_gemm2<false><<<528, 512, LDSB2, stream>>>(xph, xpl, rw, out, nullptr);
    k_row_softmax<<<NROWS, 256, 0, stream>>>(out, nullptr, NROWS);
  }
}

// Round 12
// 1382.888 us; speedup vs baseline: 11.2216x; 11.2216x over previous
//
#include <hip/hip_runtime.h>
#include <hip/hip_bf16.h>
#include <stdint.h>

typedef _Float16 f16_t;
typedef f16_t f16x8_t __attribute__((ext_vector_type(8)));
typedef f16_t f16x4_t __attribute__((ext_vector_type(4)));
typedef float f32x4_t __attribute__((ext_vector_type(4)));

#define NROWS 8192
#define DDIM  4096
#define BK 32
#define KTILES (DDIM / BK)  // 128
#define LSTR 40             // slow-path LDS stride

// ---------------- async 16B global->LDS ----------------
__device__ __forceinline__ void gload16(const void* g, void* s) {
  __builtin_amdgcn_global_load_lds(
      (const __attribute__((address_space(1))) void*)g,
      (__attribute__((address_space(3))) void*)s, 16, 0, 0);
}

// ------- fused presplit: fp32 -> (hi,lo) f16 for BOTH x and W in one launch -------
__global__ __launch_bounds__(256) void k_split2(
    const float* __restrict__ a, f16_t* __restrict__ ah, f16_t* __restrict__ al, long na,
    const float* __restrict__ b, f16_t* __restrict__ bh, f16_t* __restrict__ bl) {
  long i = ((long)blockIdx.x * 256 + threadIdx.x) * 4;
  const float* src;
  f16_t *dh, *dl;
  if (i < na) {
    src = a + i; dh = ah + i; dl = al + i;
  } else {
    const long j = i - na;
    src = b + j; dh = bh + j; dl = bl + j;
  }
  const float4 v = *reinterpret_cast<const float4*>(src);
  float vv[4] = {v.x, v.y, v.z, v.w};
  f16x4_t h, l;
#pragma unroll
  for (int c = 0; c < 4; ++c) {
    f16_t hh = (f16_t)vv[c];
    h[c] = hh;
    l[c] = (f16_t)(vv[c] - (float)hh);
  }
  *reinterpret_cast<f16x4_t*>(dh) = h;
  *reinterpret_cast<f16x4_t*>(dl) = l;
}

// ======================= GEMM1 core: split-f16 3-pass, 2 barriers/K-tile ============
// 16x16x32 fragments (proven zero-conflict). T2 swizzle: phys 16B-granule
// p = g ^ ((row>>1)&3); inverse on per-lane global source granule (gload_lds dest
// must stay linear), forward XOR on ds_read col.
// planes: 0=Ah 1=Al 2=Bh 3=Bl. LDS: [2][4][256][32] f16 = 128 KiB. 1 block/CU
// (register-bound: acc[8][4] f32x4 = 128 regs; launch_bounds(512,2) => 256-reg budget).
typedef f16_t lds4_t[4][256][BK];

__device__ __forceinline__ void gemm_core256_g1(
    const f16_t* __restrict__ pAh, const f16_t* __restrict__ pAl, long lda,
    const f16_t* __restrict__ pBh, const f16_t* __restrict__ pBl, long ldb,
    lds4_t* sm, f32x4_t (&acc)[8][4]) {
  const int t = threadIdx.x, lane = t & 63, w = t >> 6;
  const int fr = lane & 15, kg = lane >> 4;
  const int wr = (w >> 2) * 128, wc = (w & 3) * 64;
  const int w32 = w * 32;
  const int sr0 = w32 + (lane >> 2);
  const int sg = (((lane & 3) ^ ((lane >> 3) & 3)) * 8);
  const int kge = (kg ^ ((fr >> 1) & 3)) * 8;

#pragma unroll
  for (int m = 0; m < 8; ++m)
#pragma unroll
    for (int n = 0; n < 4; ++n) acc[m][n] = f32x4_t{0.f, 0.f, 0.f, 0.f};

  const f16_t* gAh = pAh + (long)sr0 * lda + sg;
  const f16_t* gAl = pAl + (long)sr0 * lda + sg;
  const f16_t* gBh = pBh + (long)sr0 * ldb + sg;
  const f16_t* gBl = pBl + (long)sr0 * ldb + sg;
  const long a16 = 16 * lda, b16 = 16 * ldb;

  auto issue = [&](int buf, int plane, const f16_t* g, long ld16, int k0) {
    gload16(g + k0, &sm[buf][plane][w32][0]);
    gload16(g + ld16 + k0, &sm[buf][plane][w32 + 16][0]);
  };

  f16x8_t ah[8], al[8], bh[4], bl[4];
  auto read8 = [&](f16x8_t(&R)[8], int buf, int plane) {
#pragma unroll
    for (int m = 0; m < 8; ++m)
      R[m] = *reinterpret_cast<const f16x8_t*>(&sm[buf][plane][wr + m * 16 + fr][kge]);
  };
  auto read4 = [&](f16x8_t(&R)[4], int buf, int plane) {
#pragma unroll
    for (int n = 0; n < 4; ++n)
      R[n] = *reinterpret_cast<const f16x8_t*>(&sm[buf][plane][wc + n * 16 + fr][kge]);
  };
  auto mfma32 = [&](f16x8_t(&A)[8], f16x8_t(&B)[4]) {
    __builtin_amdgcn_s_setprio(1);
#pragma unroll
    for (int m = 0; m < 8; ++m)
#pragma unroll
      for (int n = 0; n < 4; ++n)
        acc[m][n] = __builtin_amdgcn_mfma_f32_16x16x32_f16(A[m], B[n], acc[m][n], 0, 0, 0);
    __builtin_amdgcn_s_setprio(0);
  };

  // prologue: all 4 planes of tile 0
  issue(0, 0, gAh, a16, 0);
  issue(0, 2, gBh, b16, 0);
  issue(0, 3, gBl, b16, 0);
  issue(0, 1, gAl, a16, 0);
  asm volatile("s_waitcnt vmcnt(0)" ::: "memory");
  __builtin_amdgcn_s_barrier();

  for (int kt = 0; kt < KTILES - 1; ++kt) {
    const int c = kt & 1;
    const int k0 = (kt + 1) * BK;
    issue(c ^ 1, 0, gAh, a16, k0);
    issue(c ^ 1, 2, gBh, b16, k0);
    issue(c ^ 1, 3, gBl, b16, k0);
    read8(ah, c, 0);
    read4(bh, c, 2);
    read4(bl, c, 3);
    mfma32(ah, bh);
    mfma32(ah, bl);
    asm volatile("s_waitcnt vmcnt(6)" ::: "memory");  // Q_kt (Al of tile kt) landed
    __builtin_amdgcn_s_barrier();
    read8(al, c, 1);
    issue(c ^ 1, 1, gAl, a16, k0);
    mfma32(al, bh);
    asm volatile("s_waitcnt vmcnt(2)" ::: "memory");  // P_{kt+1} landed
    __builtin_amdgcn_s_barrier();
  }
  // peeled last tile
  {
    const int c = (KTILES - 1) & 1;
    read8(ah, c, 0);
    read4(bh, c, 2);
    read4(bl, c, 3);
    mfma32(ah, bh);
    mfma32(ah, bl);
    asm volatile("s_waitcnt vmcnt(0)" ::: "memory");  // Q_last landed
    __builtin_amdgcn_s_barrier();
    read8(al, c, 1);
    mfma32(al, bh);
  }
}

// ---------------- GEMM1 fast: xp(hi,lo f16) = split(relu(x @ W^T + b)) ----------------
__global__ __launch_bounds__(512, 2) void k_gemm1_256(
    const f16_t* __restrict__ xh, const f16_t* __restrict__ xl,
    const f16_t* __restrict__ Wh, const f16_t* __restrict__ Wl,
    const float* __restrict__ bias,
    f16_t* __restrict__ xph, f16_t* __restrict__ xpl) {
  extern __shared__ char smraw[];
  lds4_t* sm = (lds4_t*)smraw;

  int bid = (int)blockIdx.x;
  bid = (bid & 7) * 64 + (bid >> 3);  // 512 blocks, XCD-chunked (bijective)
  const int bx = bid & 15, by = bid >> 4;
  const long brow = (long)by * 256, bcol = (long)bx * 256;

  f32x4_t acc[8][4];
  gemm_core256_g1(xh + brow * DDIM, xl + brow * DDIM, DDIM,
                  Wh + bcol * DDIM, Wl + bcol * DDIM, DDIM, sm, acc);

  const int t = threadIdx.x, lane = t & 63, w = t >> 6;
  const int wr = (w >> 2) * 128, wc = (w & 3) * 64;
  const int cr = (lane >> 4) * 4, cc = lane & 15;
#pragma unroll
  for (int n = 0; n < 4; ++n) {
    const long col = bcol + wc + n * 16 + cc;
    const float bb = bias[col];
#pragma unroll
    for (int m = 0; m < 8; ++m) {
      const long row0 = brow + wr + m * 16 + cr;
#pragma unroll
      for (int r = 0; r < 4; ++r) {
        const float v = fmaxf(acc[m][n][r] + bb, 0.f);
        const f16_t h = (f16_t)v;
        xph[(row0 + r) * (long)DDIM + col] = h;
        xpl[(row0 + r) * (long)DDIM + col] = (f16_t)(v - (float)h);
      }
    }
  }
}

// ======================= GEMM2 core: Ah*(Bh+Bl), 2 barriers/K-tile ==================
// planes: 0=Ah 1=Bh 2=Bl. LDS: [2][3][256][32] f16 = 96 KiB. Parametrized K range.
typedef f16_t lds3_t[3][256][BK];

__device__ __forceinline__ void gemm_core256_g2(
    const f16_t* __restrict__ pAh, long lda,
    const f16_t* __restrict__ pBh, const f16_t* __restrict__ pBl, long ldb,
    lds3_t* sm, f32x4_t (&acc)[8][4], int kt0, int ktn) {
  const int t = threadIdx.x, lane = t & 63, w = t >> 6;
  const int fr = lane & 15, kg = lane >> 4;
  const int wr = (w >> 2) * 128, wc = (w & 3) * 64;
  const int w32 = w * 32;
  const int sr0 = w32 + (lane >> 2);
  const int sg = (((lane & 3) ^ ((lane >> 3) & 3)) * 8);
  const int kge = (kg ^ ((fr >> 1) & 3)) * 8;

#pragma unroll
  for (int m = 0; m < 8; ++m)
#pragma unroll
    for (int n = 0; n < 4; ++n) acc[m][n] = f32x4_t{0.f, 0.f, 0.f, 0.f};

  const f16_t* gAh = pAh + (long)sr0 * lda + sg;
  const f16_t* gBh = pBh + (long)sr0 * ldb + sg;
  const f16_t* gBl = pBl + (long)sr0 * ldb + sg;
  const long a16 = 16 * lda, b16 = 16 * ldb;

  auto issue = [&](int buf, int plane, const f16_t* g, long ld16, int k0) {
    gload16(g + k0, &sm[buf][plane][w32][0]);
    gload16(g + ld16 + k0, &sm[buf][plane][w32 + 16][0]);
  };

  f16x8_t ah[8], bh[4], bl[4];
  auto read8 = [&](f16x8_t(&R)[8], int buf, int plane) {
#pragma unroll
    for (int m = 0; m < 8; ++m)
      R[m] = *reinterpret_cast<const f16x8_t*>(&sm[buf][plane][wr + m * 16 + fr][kge]);
  };
  auto read4 = [&](f16x8_t(&R)[4], int buf, int plane) {
#pragma unroll
    for (int n = 0; n < 4; ++n)
      R[n] = *reinterpret_cast<const f16x8_t*>(&sm[buf][plane][wc + n * 16 + fr][kge]);
  };
  auto mfma32 = [&](f16x8_t(&A)[8], f16x8_t(&B)[4]) {
    __builtin_amdgcn_s_setprio(1);
#pragma unroll
    for (int m = 0; m < 8; ++m)
#pragma unroll
      for (int n = 0; n < 4; ++n)
        acc[m][n] = __builtin_amdgcn_mfma_f32_16x16x32_f16(A[m], B[n], acc[m][n], 0, 0, 0);
    __builtin_amdgcn_s_setprio(0);
  };

  // prologue: tile kt0
  const int kb = kt0 * BK;
  issue(0, 0, gAh, a16, kb);
  issue(0, 1, gBh, b16, kb);
  issue(0, 2, gBl, b16, kb);
  asm volatile("s_waitcnt vmcnt(0)" ::: "memory");
  __builtin_amdgcn_s_barrier();

  for (int it = 0; it < ktn - 1; ++it) {
    const int c = it & 1;
    const int k0 = (kt0 + it + 1) * BK;
    issue(c ^ 1, 0, gAh, a16, k0);
    issue(c ^ 1, 1, gBh, b16, k0);
    read8(ah, c, 0);
    read4(bh, c, 1);
    mfma32(ah, bh);
    asm volatile("s_waitcnt vmcnt(4)" ::: "memory");  // Bl(it) landed
    __builtin_amdgcn_s_barrier();
    read4(bl, c, 2);
    issue(c ^ 1, 2, gBl, b16, k0);
    mfma32(ah, bl);
    asm volatile("s_waitcnt vmcnt(2)" ::: "memory");  // Ah,Bh(it+1) landed
    __builtin_amdgcn_s_barrier();
  }
  // peeled last tile
  {
    const int c = (ktn - 1) & 1;
    read8(ah, c, 0);
    read4(bh, c, 1);
    mfma32(ah, bh);
    asm volatile("s_waitcnt vmcnt(0)" ::: "memory");  // Bl(last) landed
    __builtin_amdgcn_s_barrier();
    read4(bl, c, 2);
    mfma32(ah, bl);
  }
}

// -------- GEMM2: SPLITK: 1056 jobs = (528 lower-tri tiles) x (2 K-halves).
// khalf=0 writes scores+recency to out; khalf=1 writes raw partial to part[tidx].
// Softmax merges. Non-SPLITK fallback: 528 full-K tiles, no partial.
template <bool SPLITK>
__global__ __launch_bounds__(512, 2) void k_gemm2(
    const f16_t* __restrict__ xph, const f16_t* __restrict__ xpl,
    const float* __restrict__ rwp, float* __restrict__ out,
    float* __restrict__ part) {
  extern __shared__ char smraw[];
  lds3_t* sm = (lds3_t*)smraw;

  int id = (int)blockIdx.x;
  int tidx, khalf;
  if (SPLITK) {
    id = (id & 7) * 132 + (id >> 3);  // 1056 = 8*132, bijective XCD chunking
    khalf = (id >= 528) ? 1 : 0;
    tidx = id - khalf * 528;
  } else {
    id = (id & 7) * 66 + (id >> 3);   // 528 = 8*66
    khalf = 0;
    tidx = id;
  }
  int by = (int)((sqrtf(8.f * (float)tidx + 1.f) - 1.f) * 0.5f);
  while ((by + 1) * (by + 2) / 2 <= tidx) ++by;
  while (by * (by + 1) / 2 > tidx) --by;
  const int bx = tidx - by * (by + 1) / 2;  // 0 <= bx <= by

  const long brow = (long)by * 256, bcol = (long)bx * 256;
  f32x4_t acc[8][4];
  gemm_core256_g2(xph + brow * DDIM, DDIM,
                  xph + bcol * DDIM, xpl + bcol * DDIM, DDIM, sm, acc,
                  SPLITK ? khalf * (KTILES / 2) : 0, SPLITK ? (KTILES / 2) : KTILES);

  const int t = threadIdx.x, lane = t & 63, w = t >> 6;
  const int wr = (w >> 2) * 128, wc = (w & 3) * 64;
  const int cr = (lane >> 4) * 4, cc = lane & 15;

  if (!SPLITK || khalf == 0) {
    const float rw = rwp[0];
#pragma unroll
    for (int n = 0; n < 4; ++n) {
      const long gj = bcol + wc + n * 16 + cc;
#pragma unroll
      for (int m = 0; m < 8; ++m) {
        const long gi0 = brow + wr + m * 16 + cr;
#pragma unroll
        for (int r = 0; r < 4; ++r) {
          const long gi = gi0 + r;
          out[gi * (long)NROWS + gj] = acc[m][n][r] + rw * (float)(gi - gj);
        }
      }
    }
  } else {
    float* pt = part + (size_t)tidx * 65536;
#pragma unroll
    for (int n = 0; n < 4; ++n) {
      const int lj = wc + n * 16 + cc;
#pragma unroll
      for (int m = 0; m < 8; ++m) {
        const int li0 = wr + m * 16 + cr;
#pragma unroll
        for (int r = 0; r < 4; ++r) {
          pt[(li0 + r) * 256 + lj] = acc[m][n][r];
        }
      }
    }
  }
}

// ---------------- slow-path GEMM1 (fp32 in-LDS split; fallback) ----------------
__device__ __forceinline__ void stage_split(const float* __restrict__ src, long ld,
                                            f16_t (&hi)[128][LSTR],
                                            f16_t (&lo)[128][LSTR],
                                            int t) {
#pragma unroll
  for (int i = 0; i < 4; ++i) {
    const int f = i * 256 + t;
    const int row = f >> 3;
    const int kq = (f & 7) << 2;
    const float4 v = *reinterpret_cast<const float4*>(src + (long)row * ld + kq);
    float vv[4] = {v.x, v.y, v.z, v.w};
    f16x4_t h, l;
#pragma unroll
    for (int c = 0; c < 4; ++c) {
      f16_t hh = (f16_t)vv[c];
      h[c] = hh;
      l[c] = (f16_t)(vv[c] - (float)hh);
    }
    *reinterpret_cast<f16x4_t*>(&hi[row][kq]) = h;
    *reinterpret_cast<f16x4_t*>(&lo[row][kq]) = l;
  }
}

__global__ __launch_bounds__(256) void k_gemm1_slow(
    const float* __restrict__ x, const float* __restrict__ W,
    const float* __restrict__ bias,
    f16_t* __restrict__ xph, f16_t* __restrict__ xpl) {
  __shared__ alignas(16) f16_t Ahi[128][LSTR];
  __shared__ alignas(16) f16_t Alo[128][LSTR];
  __shared__ alignas(16) f16_t Bhi[128][LSTR];
  __shared__ alignas(16) f16_t Blo[128][LSTR];

  const long brow = (long)blockIdx.y * 128;
  const long bcol = (long)blockIdx.x * 128;
  const int t = threadIdx.x, lane = t & 63;
  const int wr = ((t >> 6) >> 1) * 64, wc = ((t >> 6) & 1) * 64;
  const int fr = lane & 15, kg = lane >> 4;

  f32x4_t acc[4][4];
#pragma unroll
  for (int m = 0; m < 4; ++m)
#pragma unroll
    for (int n = 0; n < 4; ++n) acc[m][n] = f32x4_t{0.f, 0.f, 0.f, 0.f};

  const float* Abase = x + brow * DDIM;
  const float* Bbase = W + bcol * DDIM;
  for (int k0 = 0; k0 < DDIM; k0 += BK) {
    __syncthreads();
    stage_split(Abase + k0, DDIM, Ahi, Alo, t);
    stage_split(Bbase + k0, DDIM, Bhi, Blo, t);
    __syncthreads();

    f16x8_t ah[4], al[4], bh[4], bl[4];
#pragma unroll
    for (int m = 0; m < 4; ++m) {
      ah[m] = *reinterpret_cast<const f16x8_t*>(&Ahi[wr + m * 16 + fr][kg * 8]);
      al[m] = *reinterpret_cast<const f16x8_t*>(&Alo[wr + m * 16 + fr][kg * 8]);
      bh[m] = *reinterpret_cast<const f16x8_t*>(&Bhi[wc + m * 16 + fr][kg * 8]);
      bl[m] = *reinterpret_cast<const f16x8_t*>(&Blo[wc + m * 16 + fr][kg * 8]);
    }
#pragma unroll
    for (int m = 0; m < 4; ++m)
#pragma unroll
      for (int n = 0; n < 4; ++n) {
        acc[m][n] = __builtin_amdgcn_mfma_f32_16x16x32_f16(ah[m], bh[n], acc[m][n], 0, 0, 0);
        acc[m][n] = __builtin_amdgcn_mfma_f32_16x16x32_f16(ah[m], bl[n], acc[m][n], 0, 0, 0);
        acc[m][n] = __builtin_amdgcn_mfma_f32_16x16x32_f16(al[m], bh[n], acc[m][n], 0, 0, 0);
      }
  }

  const int cr = (lane >> 4) * 4, cc = lane & 15;
#pragma unroll
  for (int n = 0; n < 4; ++n) {
    const long col = bcol + wc + n * 16 + cc;
    const float bb = bias[col];
#pragma unroll
    for (int m = 0; m < 4; ++m) {
      const long row0 = brow + wr + m * 16 + cr;
#pragma unroll
      for (int r = 0; r < 4; ++r) {
        const float v = fmaxf(acc[m][n][r] + bb, 0.f);
        const f16_t h = (f16_t)v;
        xph[(row0 + r) * (long)DDIM + col] = h;
        xpl[(row0 + r) * (long)DDIM + col] = (f16_t)(v - (float)h);
      }
    }
  }
}

// ------------- row softmax (online max+sum, single read pass), zeros for j>=i.
// part != nullptr: logits = out[i][j] + part[tile(i,j)][i%256][j%256] (K-split merge).
__global__ __launch_bounds__(256) void k_row_softmax(float* __restrict__ out,
                                                     const float* __restrict__ part,
                                                     int n) {
  const int i = blockIdx.x;
  float* row = out + (size_t)i * n;
  const int L = i;
  const int t = threadIdx.x;
  __shared__ float redm[4], reds[4];

  const int rt = i >> 8;
  const float* prow =
      part ? (part + ((size_t)(rt * (rt + 1) / 2) << 16) + ((size_t)(i & 255) << 8)) : nullptr;

  auto val = [&](int j) -> float {
    float v = row[j];
    if (part) v += prow[((size_t)(j >> 8) << 16) + (j & 255)];
    return v;
  };

  float m = -3.0e38f, s = 0.f;  // finite sentinel: avoids (-inf)-(-inf)=NaN in combines
  for (int j = t; j < L; j += 256) {
    const float v = val(j);
    const float M = fmaxf(m, v);
    s = s * __expf(m - M) + __expf(v - M);
    m = M;
  }
#pragma unroll
  for (int o = 32; o > 0; o >>= 1) {
    const float om = __shfl_down(m, o, 64);
    const float os = __shfl_down(s, o, 64);
    const float M = fmaxf(m, om);
    s = s * __expf(m - M) + os * __expf(om - M);
    m = M;
  }
  if ((t & 63) == 0) { redm[t >> 6] = m; reds[t >> 6] = s; }
  __syncthreads();
  const float M4 = fmaxf(fmaxf(redm[0], redm[1]), fmaxf(redm[2], redm[3]));
  const float S4 = reds[0] * __expf(redm[0] - M4) + reds[1] * __expf(redm[1] - M4) +
                   reds[2] * __expf(redm[2] - M4) + reds[3] * __expf(redm[3] - M4);
  const float inv = (L > 0) ? 1.f / S4 : 0.f;

  for (int j = t; j < n; j += 256) {
    row[j] = (j < L) ? __expf(val(j) - M4) * inv : 0.f;
  }
}

extern "C" void kernel_launch(void* const* d_in, const int* in_sizes, int n_in,
                              void* d_out, int out_size, void* d_ws, size_t ws_size,
                              hipStream_t stream) {
  (void)in_sizes; (void)n_in; (void)out_size;
  const float* x = (const float*)d_in[0];
  const float* W = (const float*)d_in[1];
  const float* b = (const float*)d_in[2];
  const float* rw = (const float*)d_in[3];
  float* out = (float*)d_out;

  const size_t NX = (size_t)NROWS * DDIM;
  const size_t NW = (size_t)DDIM * DDIM;
  char* ws = (char*)d_ws;
  f16_t* xph = (f16_t*)ws;
  f16_t* xpl = (f16_t*)(ws + NX * 2);

  const int LDSB1 = 2 * 4 * 256 * BK * 2;  // 131072 B
  const int LDSB2 = 2 * 3 * 256 * BK * 2;  // 98304 B
  (void)hipFuncSetAttribute(reinterpret_cast<const void*>(k_gemm1_256),
                            hipFuncAttributeMaxDynamicSharedMemorySize, LDSB1);
  (void)hipFuncSetAttribute(reinterpret_cast<const void*>(&k_gemm2<true>),
                            hipFuncAttributeMaxDynamicSharedMemorySize, LDSB2);
  (void)hipFuncSetAttribute(reinterpret_cast<const void*>(&k_gemm2<false>),
                            hipFuncAttributeMaxDynamicSharedMemorySize, LDSB2);

  const size_t need_full = NX * 4 /*xph,xpl*/ + NX * 4 /*xh,xl*/ + NW * 4 /*Wh,Wl*/;
  if (ws_size >= need_full) {
    f16_t* xh = (f16_t*)(ws + NX * 4);
    f16_t* xl = (f16_t*)(ws + NX * 6);
    f16_t* Wh = (f16_t*)(ws + NX * 8);
    f16_t* Wl = (f16_t*)(ws + NX * 8 + NW * 2);
    // K-split partial buffer reuses the xh/xl region (dead after k_gemm1_256):
    // 528 tiles * 65536 * 4B = 138.4 MB < NX*4 + NW*4 = 201 MB available.
    float* part = (float*)(ws + NX * 4);
    k_split2<<<(int)((NX + NW) / 1024), 256, 0, stream>>>(x, xh, xl, (long)NX, W, Wh, Wl);
    k_gemm1_256<<<512, 512, LDSB1, stream>>>(xh, xl, Wh, Wl, b, xph, xpl);
    k_gemm2<true><<<1056, 512, LDSB2, stream>>>(xph, xpl, rw, out, part);
    k_row_softmax<<<NROWS, 256, 0, stream>>>(out, part, NROWS);
  } else {
    k_gemm1_slow<<<dim3(DDIM / 128, NROWS / 128), 256, 0, stream>>>(x, W, b, xph, xpl);
    k_gemm2<false><<<528, 512, LDSB2, stream>>>(xph, xpl, rw, out, nullptr);
    k_row_softmax<<<NROWS, 256, 0, stream>>>(out, nullptr, NROWS);
  }
}